// Round 23
// baseline (49.914 us; speedup 1.0000x reference)
//
#include <hip/hip_runtime.h>

#define NB 16
#define NL 1024
#define ND 64
#define NW 20
#define CH 8                    // l's per block (rolling) — 2048 blocks
#define THR 0.3f

typedef float f32x4 __attribute__((ext_vector_type(4)));

// Rolling-window, 256 threads per (b, 8-l chunk), strided row ownership
// (1KB contiguous per store instr), slim epilogue (raw v_sqrt/v_rcp),
// ping-pong output register sets, PLAIN stores (R22: dropping nt let L2
// buffer writes and overlap write-back with compute, 55.9->47.2us; nt's
// shallow buffering was the serializer all along).
// R23: CH=8 -> 2048 blocks (8/CU, ~6 resident): block retirement staggers
// init so later blocks' staging/init overlaps in-flight stores, attacking
// the ~5us lockstep prologue exposure. (R20's CH=8 null was nt-regime.)
// EPILOGUE eps EXACT: den = sdu*seu + 19e-8 == 19*(sd*se + 1e-8) (R8).
// RULES: no runtime indexing into register arrays (R5); no __launch_bounds__
// (R3/R4).
__global__ void dyn_corr_kernel(
    const float* __restrict__ x, float* __restrict__ out)
{
    const int blk = blockIdx.x;            // 0..2047
    const int b   = blk >> 7;              // 128 chunks per batch
    const int l0  = (blk & 127) * CH;
    const int t   = threadIdx.x;           // 0..255

    const int NROW = NW - 1 + CH;          // 27 staged rows
    __shared__ float win[NW - 1 + CH][ND]; // 6912 B

    const float* xb = x + ((size_t)b * NL) * ND;

    #pragma unroll
    for (int i = 0; i < 2; ++i) {
        int s = t + i * 256;               // valid < 432
        if (s < NROW * 16) {
            int w    = s >> 4;
            int c4   = (s & 15) << 2;
            int lsrc = l0 - (NW - 1) + w;
            f32x4 v = {0.f, 0.f, 0.f, 0.f};
            if (lsrc >= 0) v = *(const f32x4*)&xb[(size_t)lsrc * ND + c4];
            *(f32x4*)&win[w][c4] = v;
        }
    }
    __syncthreads();                       // win read-only from here on

    const int q  = t >> 6;                 // wave 0..3 -> rows 16q..16q+15
    const int g  = (t >> 4) & 3;           // row-group within wave
    const int tc = t & 15;                 // col group
    const int r0 = (q << 4) + g;           // row(i) = r0 + 4*i
    const int e0 = tc << 2;                // cols e0..e0+3

    float acc[4][4] = {};
    float rs[4] = {}, rq[4] = {};
    float cs[4] = {}, cq[4] = {};

    #pragma unroll
    for (int w = 0; w < NW; ++w) {
        float ar[4];
        ar[0] = win[w][r0];
        ar[1] = win[w][r0 + 4];
        ar[2] = win[w][r0 + 8];
        ar[3] = win[w][r0 + 12];
        f32x4 b0 = *(const f32x4*)&win[w][e0];
        float br[4] = {b0.x, b0.y, b0.z, b0.w};
        #pragma unroll
        for (int i = 0; i < 4; ++i) {
            rs[i] += ar[i];
            rq[i]  = fmaf(ar[i], ar[i], rq[i]);
            #pragma unroll
            for (int j = 0; j < 4; ++j)
                acc[i][j] = fmaf(ar[i], br[j], acc[i][j]);
        }
        #pragma unroll
        for (int j = 0; j < 4; ++j) {
            cs[j] += br[j];
            cq[j]  = fmaf(br[j], br[j], cq[j]);
        }
    }

    const float invW  = 1.0f / NW;
    const float EPS19 = 19e-8f;
    float* obase = out + ((size_t)b * NL + l0) * (ND * ND);

    #define EPI(S, O0, O1, O2, O3)                                         \
    {                                                                      \
        float sdu[4], seu[4], mc[4];                                       \
        _Pragma("unroll")                                                  \
        for (int i = 0; i < 4; ++i) {                                      \
            float qv = fmaf(-rs[i] * invW, rs[i], rq[i]);                  \
            sdu[i] = __builtin_amdgcn_sqrtf(qv);                           \
        }                                                                  \
        _Pragma("unroll")                                                  \
        for (int j = 0; j < 4; ++j) {                                      \
            mc[j] = cs[j] * invW;                                          \
            float qv = fmaf(-cs[j], mc[j], cq[j]);                         \
            seu[j] = __builtin_amdgcn_sqrtf(qv);                           \
        }                                                                  \
        float cv, rr;                                                      \
        cv = fmaf(-rs[0], mc[0], acc[0][0]);                               \
        rr = __builtin_amdgcn_rcpf(fmaf(sdu[0], seu[0], EPS19));           \
        O0.x = fmaxf(fmaf(fabsf(cv), rr, -THR), 0.0f);                     \
        cv = fmaf(-rs[0], mc[1], acc[0][1]);                               \
        rr = __builtin_amdgcn_rcpf(fmaf(sdu[0], seu[1], EPS19));           \
        O0.y = fmaxf(fmaf(fabsf(cv), rr, -THR), 0.0f);                     \
        cv = fmaf(-rs[0], mc[2], acc[0][2]);                               \
        rr = __builtin_amdgcn_rcpf(fmaf(sdu[0], seu[2], EPS19));           \
        O0.z = fmaxf(fmaf(fabsf(cv), rr, -THR), 0.0f);                     \
        cv = fmaf(-rs[0], mc[3], acc[0][3]);                               \
        rr = __builtin_amdgcn_rcpf(fmaf(sdu[0], seu[3], EPS19));           \
        O0.w = fmaxf(fmaf(fabsf(cv), rr, -THR), 0.0f);                     \
        cv = fmaf(-rs[1], mc[0], acc[1][0]);                               \
        rr = __builtin_amdgcn_rcpf(fmaf(sdu[1], seu[0], EPS19));           \
        O1.x = fmaxf(fmaf(fabsf(cv), rr, -THR), 0.0f);                     \
        cv = fmaf(-rs[1], mc[1], acc[1][1]);                               \
        rr = __builtin_amdgcn_rcpf(fmaf(sdu[1], seu[1], EPS19));           \
        O1.y = fmaxf(fmaf(fabsf(cv), rr, -THR), 0.0f);                     \
        cv = fmaf(-rs[1], mc[2], acc[1][2]);                               \
        rr = __builtin_amdgcn_rcpf(fmaf(sdu[1], seu[2], EPS19));           \
        O1.z = fmaxf(fmaf(fabsf(cv), rr, -THR), 0.0f);                     \
        cv = fmaf(-rs[1], mc[3], acc[1][3]);                               \
        rr = __builtin_amdgcn_rcpf(fmaf(sdu[1], seu[3], EPS19));           \
        O1.w = fmaxf(fmaf(fabsf(cv), rr, -THR), 0.0f);                     \
        cv = fmaf(-rs[2], mc[0], acc[2][0]);                               \
        rr = __builtin_amdgcn_rcpf(fmaf(sdu[2], seu[0], EPS19));           \
        O2.x = fmaxf(fmaf(fabsf(cv), rr, -THR), 0.0f);                     \
        cv = fmaf(-rs[2], mc[1], acc[2][1]);                               \
        rr = __builtin_amdgcn_rcpf(fmaf(sdu[2], seu[1], EPS19));           \
        O2.y = fmaxf(fmaf(fabsf(cv), rr, -THR), 0.0f);                     \
        cv = fmaf(-rs[2], mc[2], acc[2][2]);                               \
        rr = __builtin_amdgcn_rcpf(fmaf(sdu[2], seu[2], EPS19));           \
        O2.z = fmaxf(fmaf(fabsf(cv), rr, -THR), 0.0f);                     \
        cv = fmaf(-rs[2], mc[3], acc[2][3]);                               \
        rr = __builtin_amdgcn_rcpf(fmaf(sdu[2], seu[3], EPS19));           \
        O2.w = fmaxf(fmaf(fabsf(cv), rr, -THR), 0.0f);                     \
        cv = fmaf(-rs[3], mc[0], acc[3][0]);                               \
        rr = __builtin_amdgcn_rcpf(fmaf(sdu[3], seu[0], EPS19));           \
        O3.x = fmaxf(fmaf(fabsf(cv), rr, -THR), 0.0f);                     \
        cv = fmaf(-rs[3], mc[1], acc[3][1]);                               \
        rr = __builtin_amdgcn_rcpf(fmaf(sdu[3], seu[1], EPS19));           \
        O3.y = fmaxf(fmaf(fabsf(cv), rr, -THR), 0.0f);                     \
        cv = fmaf(-rs[3], mc[2], acc[3][2]);                               \
        rr = __builtin_amdgcn_rcpf(fmaf(sdu[3], seu[2], EPS19));           \
        O3.z = fmaxf(fmaf(fabsf(cv), rr, -THR), 0.0f);                     \
        cv = fmaf(-rs[3], mc[3], acc[3][3]);                               \
        rr = __builtin_amdgcn_rcpf(fmaf(sdu[3], seu[3], EPS19));           \
        O3.w = fmaxf(fmaf(fabsf(cv), rr, -THR), 0.0f);                     \
    }

    #define STORE4(S, O0, O1, O2, O3)                                      \
    {                                                                      \
        float* ob_ = obase + (size_t)(S) * (ND * ND);                      \
        *(f32x4*)&ob_[(r0     ) * ND + e0] = O0;                           \
        *(f32x4*)&ob_[(r0 +  4) * ND + e0] = O1;                           \
        *(f32x4*)&ob_[(r0 +  8) * ND + e0] = O2;                           \
        *(f32x4*)&ob_[(r0 + 12) * ND + e0] = O3;                           \
    }

    #define UPDATE(S)                                                      \
    {                                                                      \
        float an[4], ao[4];                                                \
        an[0] = win[(S) + NW][r0];                                         \
        an[1] = win[(S) + NW][r0 + 4];                                     \
        an[2] = win[(S) + NW][r0 + 8];                                     \
        an[3] = win[(S) + NW][r0 + 12];                                    \
        ao[0] = win[(S)][r0];                                              \
        ao[1] = win[(S)][r0 + 4];                                          \
        ao[2] = win[(S)][r0 + 8];                                          \
        ao[3] = win[(S)][r0 + 12];                                         \
        f32x4 nb  = *(const f32x4*)&win[(S) + NW][e0];                     \
        f32x4 obv = *(const f32x4*)&win[(S)][e0];                          \
        float bn[4] = {nb.x, nb.y, nb.z, nb.w};                            \
        float bo[4] = {obv.x, obv.y, obv.z, obv.w};                        \
        _Pragma("unroll")                                                  \
        for (int i = 0; i < 4; ++i) {                                      \
            rs[i] += an[i] - ao[i];                                        \
            rq[i]  = fmaf(an[i], an[i], fmaf(-ao[i], ao[i], rq[i]));       \
            _Pragma("unroll")                                              \
            for (int j = 0; j < 4; ++j)                                    \
                acc[i][j] = fmaf(an[i], bn[j], fmaf(-ao[i], bo[j], acc[i][j])); \
        }                                                                  \
        _Pragma("unroll")                                                  \
        for (int j = 0; j < 4; ++j) {                                      \
            cs[j] += bn[j] - bo[j];                                        \
            cq[j]  = fmaf(bn[j], bn[j], fmaf(-bo[j], bo[j], cq[j]));       \
        }                                                                  \
    }

    f32x4 oA0, oA1, oA2, oA3;
    f32x4 oB0, oB1, oB2, oB3;

    EPI(0, oA0, oA1, oA2, oA3);
    UPDATE(0);
    STORE4(0, oA0, oA1, oA2, oA3);

    #pragma unroll 1
    for (int k = 0; k < 3; ++k) {
        int s1 = 2 * k + 1;
        int s2 = 2 * k + 2;
        EPI(s1, oB0, oB1, oB2, oB3);
        UPDATE(s1);
        STORE4(s1, oB0, oB1, oB2, oB3);
        EPI(s2, oA0, oA1, oA2, oA3);
        UPDATE(s2);
        STORE4(s2, oA0, oA1, oA2, oA3);
    }

    EPI(7, oB0, oB1, oB2, oB3);
    STORE4(7, oB0, oB1, oB2, oB3);

    #undef EPI
    #undef STORE4
    #undef UPDATE
}

extern "C" void kernel_launch(void* const* d_in, const int* in_sizes, int n_in,
                              void* d_out, int out_size, void* d_ws, size_t ws_size,
                              hipStream_t stream) {
    const float* x = (const float*)d_in[0];
    float* out = (float*)d_out;
    dim3 grid(NB * (NL / CH));
    dim3 block(256);
    hipLaunchKernelGGL(dyn_corr_kernel, grid, block, 0, stream, x, out);
}

// Round 24
// 47.451 us; speedup vs baseline: 1.0519x; 1.0519x over previous
//
#include <hip/hip_runtime.h>

#define NB 16
#define NL 1024
#define ND 64
#define NW 20
#define CH 32                   // l's per block (rolling) — 512 blocks
#define THR 0.3f

typedef float f32x4 __attribute__((ext_vector_type(4)));

// Rolling-window, 256 threads per (b, 32-l chunk), strided row ownership
// (1KB contiguous per store instr), slim epilogue (raw v_sqrt/v_rcp),
// ping-pong output register sets, PLAIN stores (R22: nt's shallow
// buffering serialized drain vs compute; L2 write-buffering overlaps them,
// 55.9->47.2us).
// R24: CH=32 (512 blocks, 2/CU). CH 8->16 gave -2.7us by halving init work;
// halve it again. All blocks co-resident either way (prologue exposure
// unchanged); total init instructions and staging re-fetch halve.
// EPILOGUE eps EXACT: den = sdu*seu + 19e-8 == 19*(sd*se + 1e-8) (R8).
// RULES: no runtime indexing into register arrays (R5); no __launch_bounds__
// (R3/R4).
__global__ void dyn_corr_kernel(
    const float* __restrict__ x, float* __restrict__ out)
{
    const int blk = blockIdx.x;            // 0..511
    const int b   = blk >> 5;              // 32 chunks per batch
    const int l0  = (blk & 31) * CH;
    const int t   = threadIdx.x;           // 0..255

    const int NROW = NW - 1 + CH;          // 51 staged rows
    __shared__ float win[NW - 1 + CH][ND]; // 13056 B

    const float* xb = x + ((size_t)b * NL) * ND;

    #pragma unroll
    for (int i = 0; i < 4; ++i) {
        int s = t + i * 256;               // valid < 816
        if (s < NROW * 16) {
            int w    = s >> 4;
            int c4   = (s & 15) << 2;
            int lsrc = l0 - (NW - 1) + w;
            f32x4 v = {0.f, 0.f, 0.f, 0.f};
            if (lsrc >= 0) v = *(const f32x4*)&xb[(size_t)lsrc * ND + c4];
            *(f32x4*)&win[w][c4] = v;
        }
    }
    __syncthreads();                       // win read-only from here on

    const int q  = t >> 6;                 // wave 0..3 -> rows 16q..16q+15
    const int g  = (t >> 4) & 3;           // row-group within wave
    const int tc = t & 15;                 // col group
    const int r0 = (q << 4) + g;           // row(i) = r0 + 4*i
    const int e0 = tc << 2;                // cols e0..e0+3

    float acc[4][4] = {};
    float rs[4] = {}, rq[4] = {};
    float cs[4] = {}, cq[4] = {};

    #pragma unroll
    for (int w = 0; w < NW; ++w) {
        float ar[4];
        ar[0] = win[w][r0];
        ar[1] = win[w][r0 + 4];
        ar[2] = win[w][r0 + 8];
        ar[3] = win[w][r0 + 12];
        f32x4 b0 = *(const f32x4*)&win[w][e0];
        float br[4] = {b0.x, b0.y, b0.z, b0.w};
        #pragma unroll
        for (int i = 0; i < 4; ++i) {
            rs[i] += ar[i];
            rq[i]  = fmaf(ar[i], ar[i], rq[i]);
            #pragma unroll
            for (int j = 0; j < 4; ++j)
                acc[i][j] = fmaf(ar[i], br[j], acc[i][j]);
        }
        #pragma unroll
        for (int j = 0; j < 4; ++j) {
            cs[j] += br[j];
            cq[j]  = fmaf(br[j], br[j], cq[j]);
        }
    }

    const float invW  = 1.0f / NW;
    const float EPS19 = 19e-8f;
    float* obase = out + ((size_t)b * NL + l0) * (ND * ND);

    #define EPI(S, O0, O1, O2, O3)                                         \
    {                                                                      \
        float sdu[4], seu[4], mc[4];                                       \
        _Pragma("unroll")                                                  \
        for (int i = 0; i < 4; ++i) {                                      \
            float qv = fmaf(-rs[i] * invW, rs[i], rq[i]);                  \
            sdu[i] = __builtin_amdgcn_sqrtf(qv);                           \
        }                                                                  \
        _Pragma("unroll")                                                  \
        for (int j = 0; j < 4; ++j) {                                      \
            mc[j] = cs[j] * invW;                                          \
            float qv = fmaf(-cs[j], mc[j], cq[j]);                         \
            seu[j] = __builtin_amdgcn_sqrtf(qv);                           \
        }                                                                  \
        float cv, rr;                                                      \
        cv = fmaf(-rs[0], mc[0], acc[0][0]);                               \
        rr = __builtin_amdgcn_rcpf(fmaf(sdu[0], seu[0], EPS19));           \
        O0.x = fmaxf(fmaf(fabsf(cv), rr, -THR), 0.0f);                     \
        cv = fmaf(-rs[0], mc[1], acc[0][1]);                               \
        rr = __builtin_amdgcn_rcpf(fmaf(sdu[0], seu[1], EPS19));           \
        O0.y = fmaxf(fmaf(fabsf(cv), rr, -THR), 0.0f);                     \
        cv = fmaf(-rs[0], mc[2], acc[0][2]);                               \
        rr = __builtin_amdgcn_rcpf(fmaf(sdu[0], seu[2], EPS19));           \
        O0.z = fmaxf(fmaf(fabsf(cv), rr, -THR), 0.0f);                     \
        cv = fmaf(-rs[0], mc[3], acc[0][3]);                               \
        rr = __builtin_amdgcn_rcpf(fmaf(sdu[0], seu[3], EPS19));           \
        O0.w = fmaxf(fmaf(fabsf(cv), rr, -THR), 0.0f);                     \
        cv = fmaf(-rs[1], mc[0], acc[1][0]);                               \
        rr = __builtin_amdgcn_rcpf(fmaf(sdu[1], seu[0], EPS19));           \
        O1.x = fmaxf(fmaf(fabsf(cv), rr, -THR), 0.0f);                     \
        cv = fmaf(-rs[1], mc[1], acc[1][1]);                               \
        rr = __builtin_amdgcn_rcpf(fmaf(sdu[1], seu[1], EPS19));           \
        O1.y = fmaxf(fmaf(fabsf(cv), rr, -THR), 0.0f);                     \
        cv = fmaf(-rs[1], mc[2], acc[1][2]);                               \
        rr = __builtin_amdgcn_rcpf(fmaf(sdu[1], seu[2], EPS19));           \
        O1.z = fmaxf(fmaf(fabsf(cv), rr, -THR), 0.0f);                     \
        cv = fmaf(-rs[1], mc[3], acc[1][3]);                               \
        rr = __builtin_amdgcn_rcpf(fmaf(sdu[1], seu[3], EPS19));           \
        O1.w = fmaxf(fmaf(fabsf(cv), rr, -THR), 0.0f);                     \
        cv = fmaf(-rs[2], mc[0], acc[2][0]);                               \
        rr = __builtin_amdgcn_rcpf(fmaf(sdu[2], seu[0], EPS19));           \
        O2.x = fmaxf(fmaf(fabsf(cv), rr, -THR), 0.0f);                     \
        cv = fmaf(-rs[2], mc[1], acc[2][1]);                               \
        rr = __builtin_amdgcn_rcpf(fmaf(sdu[2], seu[1], EPS19));           \
        O2.y = fmaxf(fmaf(fabsf(cv), rr, -THR), 0.0f);                     \
        cv = fmaf(-rs[2], mc[2], acc[2][2]);                               \
        rr = __builtin_amdgcn_rcpf(fmaf(sdu[2], seu[2], EPS19));           \
        O2.z = fmaxf(fmaf(fabsf(cv), rr, -THR), 0.0f);                     \
        cv = fmaf(-rs[2], mc[3], acc[2][3]);                               \
        rr = __builtin_amdgcn_rcpf(fmaf(sdu[2], seu[3], EPS19));           \
        O2.w = fmaxf(fmaf(fabsf(cv), rr, -THR), 0.0f);                     \
        cv = fmaf(-rs[3], mc[0], acc[3][0]);                               \
        rr = __builtin_amdgcn_rcpf(fmaf(sdu[3], seu[0], EPS19));           \
        O3.x = fmaxf(fmaf(fabsf(cv), rr, -THR), 0.0f);                     \
        cv = fmaf(-rs[3], mc[1], acc[3][1]);                               \
        rr = __builtin_amdgcn_rcpf(fmaf(sdu[3], seu[1], EPS19));           \
        O3.y = fmaxf(fmaf(fabsf(cv), rr, -THR), 0.0f);                     \
        cv = fmaf(-rs[3], mc[2], acc[3][2]);                               \
        rr = __builtin_amdgcn_rcpf(fmaf(sdu[3], seu[2], EPS19));           \
        O3.z = fmaxf(fmaf(fabsf(cv), rr, -THR), 0.0f);                     \
        cv = fmaf(-rs[3], mc[3], acc[3][3]);                               \
        rr = __builtin_amdgcn_rcpf(fmaf(sdu[3], seu[3], EPS19));           \
        O3.w = fmaxf(fmaf(fabsf(cv), rr, -THR), 0.0f);                     \
    }

    #define STORE4(S, O0, O1, O2, O3)                                      \
    {                                                                      \
        float* ob_ = obase + (size_t)(S) * (ND * ND);                      \
        *(f32x4*)&ob_[(r0     ) * ND + e0] = O0;                           \
        *(f32x4*)&ob_[(r0 +  4) * ND + e0] = O1;                           \
        *(f32x4*)&ob_[(r0 +  8) * ND + e0] = O2;                           \
        *(f32x4*)&ob_[(r0 + 12) * ND + e0] = O3;                           \
    }

    #define UPDATE(S)                                                      \
    {                                                                      \
        float an[4], ao[4];                                                \
        an[0] = win[(S) + NW][r0];                                         \
        an[1] = win[(S) + NW][r0 + 4];                                     \
        an[2] = win[(S) + NW][r0 + 8];                                     \
        an[3] = win[(S) + NW][r0 + 12];                                    \
        ao[0] = win[(S)][r0];                                              \
        ao[1] = win[(S)][r0 + 4];                                          \
        ao[2] = win[(S)][r0 + 8];                                          \
        ao[3] = win[(S)][r0 + 12];                                         \
        f32x4 nb  = *(const f32x4*)&win[(S) + NW][e0];                     \
        f32x4 obv = *(const f32x4*)&win[(S)][e0];                          \
        float bn[4] = {nb.x, nb.y, nb.z, nb.w};                            \
        float bo[4] = {obv.x, obv.y, obv.z, obv.w};                        \
        _Pragma("unroll")                                                  \
        for (int i = 0; i < 4; ++i) {                                      \
            rs[i] += an[i] - ao[i];                                        \
            rq[i]  = fmaf(an[i], an[i], fmaf(-ao[i], ao[i], rq[i]));       \
            _Pragma("unroll")                                              \
            for (int j = 0; j < 4; ++j)                                    \
                acc[i][j] = fmaf(an[i], bn[j], fmaf(-ao[i], bo[j], acc[i][j])); \
        }                                                                  \
        _Pragma("unroll")                                                  \
        for (int j = 0; j < 4; ++j) {                                      \
            cs[j] += bn[j] - bo[j];                                        \
            cq[j]  = fmaf(bn[j], bn[j], fmaf(-bo[j], bo[j], cq[j]));       \
        }                                                                  \
    }

    f32x4 oA0, oA1, oA2, oA3;
    f32x4 oB0, oB1, oB2, oB3;

    EPI(0, oA0, oA1, oA2, oA3);
    UPDATE(0);
    STORE4(0, oA0, oA1, oA2, oA3);

    #pragma unroll 1
    for (int k = 0; k < 15; ++k) {
        int s1 = 2 * k + 1;
        int s2 = 2 * k + 2;
        EPI(s1, oB0, oB1, oB2, oB3);
        UPDATE(s1);
        STORE4(s1, oB0, oB1, oB2, oB3);
        EPI(s2, oA0, oA1, oA2, oA3);
        UPDATE(s2);
        STORE4(s2, oA0, oA1, oA2, oA3);
    }

    EPI(31, oB0, oB1, oB2, oB3);
    STORE4(31, oB0, oB1, oB2, oB3);

    #undef EPI
    #undef STORE4
    #undef UPDATE
}

extern "C" void kernel_launch(void* const* d_in, const int* in_sizes, int n_in,
                              void* d_out, int out_size, void* d_ws, size_t ws_size,
                              hipStream_t stream) {
    const float* x = (const float*)d_in[0];
    float* out = (float*)d_out;
    dim3 grid(NB * (NL / CH));
    dim3 block(256);
    hipLaunchKernelGGL(dyn_corr_kernel, grid, block, 0, stream, x, out);
}